// Round 4
// baseline (131.274 us; speedup 1.0000x reference)
//
#include <hip/hip_runtime.h>

// Problem constants: B=2, T=2048, D=1024, H=16, DH=64
#define TT 2048
#define DD 1024
#define HH 16
#define DHH 64

typedef __attribute__((ext_vector_type(4)))  float  f32x4;
typedef __attribute__((ext_vector_type(16))) float  f32x16;
typedef __attribute__((ext_vector_type(8)))  short  bf16x8;   // 8 bf16 in 4 VGPRs
typedef __attribute__((ext_vector_type(4)))  float  f4;
typedef __attribute__((ext_vector_type(4)))  unsigned short u16x4;
typedef __attribute__((ext_vector_type(4)))  unsigned int   u32x4;

// fp32 -> bf16 round-to-nearest-even
__device__ __forceinline__ unsigned short f2b(float f) {
    union { float f; unsigned int u; } v; v.f = f;
    unsigned int r = v.u + 0x7fffu + ((v.u >> 16) & 1u);
    return (unsigned short)(r >> 16);
}

// async global->LDS, 16B per lane; LDS dest must be wave-uniform base + lane*16
__device__ __forceinline__ void gl_lds16(const void* g, void* l) {
    __builtin_amdgcn_global_load_lds(
        (const __attribute__((address_space(1))) unsigned int*)g,
        (__attribute__((address_space(3))) unsigned int*)l, 16, 0, 0);
}

__device__ __forceinline__ f32x16 mfma32(bf16x8 a, bf16x8 b, f32x16 c) {
    return __builtin_amdgcn_mfma_f32_32x32x16_bf16(a, b, c, 0, 0, 0);
}

// 2^x via v_exp_f32
__device__ __forceinline__ float fexp2(float x) {
    float r; asm("v_exp_f32 %0, %1" : "=v"(r) : "v"(x)); return r;
}

// pack two f32 -> u32 of 2 bf16 (lo = a, hi = b)
__device__ __forceinline__ unsigned int pkbf(float a, float b) {
    unsigned int r;
    asm("v_cvt_pk_bf16_f32 %0, %1, %2" : "=v"(r) : "v"(a), "v"(b));
    return r;
}

// v_permlane32_swap_b32: a'[32+i]=b[i]; b'[i]=a[32+i]
__device__ __forceinline__ void pl32swap(unsigned int& a, unsigned int& b) {
    asm("v_permlane32_swap_b32 %0, %1" : "+v"(a), "+v"(b));
}

__device__ __forceinline__ bf16x8 u2h(u32x4 u) {
    union { u32x4 u; bf16x8 h; } x; x.u = u; return x.h;
}

// ---------------- fp32 -> bf16 conversion (vectorized) ----------------
__global__ void f2b_kernel(const float* __restrict__ s, unsigned short* __restrict__ d, int n4) {
    int i = blockIdx.x * blockDim.x + threadIdx.x;
    int stride = gridDim.x * blockDim.x;
    for (; i < n4; i += stride) {
        f4 v = ((const f4*)s)[i];
        u16x4 o;
        o[0] = f2b(v[0]); o[1] = f2b(v[1]); o[2] = f2b(v[2]); o[3] = f2b(v[3]);
        ((u16x4*)d)[i] = o;
    }
}

// ---------------- GEMM: C[M,N] = A[M,K] * Bm[N,K]^T + bias ----------------
// 128 x BN tile, 4 waves (2x2), 2-phase double-buffered LDS staging.
// MODE 0 (BN=128): QKV epilogue -> q scaled by 0.125*log2e, k [B,H,T,DH], vt [B,H,DH,T]
// MODE 1 (BN=64):  fp32 out + bias (final projection; BN=64 -> 512 blocks)
template<int BN, int MODE>
__global__ __launch_bounds__(256) void gemm_bt(
    const unsigned short* __restrict__ A, const unsigned short* __restrict__ Bm,
    const float* __restrict__ bias, int N, int K,
    unsigned short* __restrict__ q, unsigned short* __restrict__ k,
    unsigned short* __restrict__ vt, float* __restrict__ outf)
{
    constexpr int NB  = BN / 32;        // B-frags per wave
    constexpr int ASZ = 128 * 32;       // shorts per A tile
    constexpr int BSZ = BN * 32;        // shorts per B tile
    __shared__ unsigned short lds[2 * (ASZ + BSZ)];

    int tid = threadIdx.x;
    int l = tid & 63, w = tid >> 6;
    int wr = w >> 1, wc = w & 1;
    int lr = l & 15, lk = (l >> 4) * 8;
    int bm = blockIdx.y, bn = blockIdx.x;

    f32x4 acc[4][NB] = {};

    const unsigned short* Ag = A + (size_t)(bm * 128) * K;
    const unsigned short* Bg = Bm + (size_t)(bn * BN) * K;

    auto stage = [&](int buf, int k0) {
        unsigned short* As = lds + buf * (ASZ + BSZ);
        unsigned short* Bs = As + ASZ;
#pragma unroll
        for (int r = 0; r < 2; ++r) {
            int e = r * 256 + tid;
            int row = e >> 2, kc = (e & 3) * 8;
            gl_lds16(Ag + (size_t)row * K + k0 + kc, &As[e * 8]);
        }
#pragma unroll
        for (int r = 0; r < BN / 64; ++r) {
            int e = r * 256 + tid;
            int row = e >> 2, kc = (e & 3) * 8;
            gl_lds16(Bg + (size_t)row * K + k0 + kc, &Bs[e * 8]);
        }
    };

    stage(0, 0);
    __syncthreads();
    int cur = 0;
    for (int k0 = 0; k0 < K; k0 += 32) {
        if (k0 + 32 < K) stage(cur ^ 1, k0 + 32);   // prefetch next tile
        const unsigned short* As = lds + cur * (ASZ + BSZ);
        const unsigned short* Bs = As + ASZ;
        bf16x8 a[4], b[NB];
#pragma unroll
        for (int i = 0; i < 4; ++i)
            a[i] = *(const bf16x8*)&As[(wr * 64 + i * 16 + lr) * 32 + lk];
#pragma unroll
        for (int j = 0; j < NB; ++j)
            b[j] = *(const bf16x8*)&Bs[(wc * (BN / 2) + j * 16 + lr) * 32 + lk];
        __builtin_amdgcn_s_setprio(1);
#pragma unroll
        for (int i = 0; i < 4; ++i)
#pragma unroll
            for (int j = 0; j < NB; ++j)
                acc[i][j] = __builtin_amdgcn_mfma_f32_16x16x32_bf16(a[i], b[j], acc[i][j], 0, 0, 0);
        __builtin_amdgcn_s_setprio(0);
        __syncthreads();
        cur ^= 1;
    }

#pragma unroll
    for (int i = 0; i < 4; ++i) {
#pragma unroll
        for (int j = 0; j < NB; ++j) {
            int row0 = bm * 128 + wr * 64 + i * 16 + (l >> 4) * 4;
            int col  = bn * BN + wc * (BN / 2) + j * 16 + (l & 15);
            float bv = bias[col];
#pragma unroll
            for (int r = 0; r < 4; ++r) {
                float val = acc[i][j][r] + bv;
                int m = row0 + r;
                if (MODE == 0) {
                    int which = col >> 10, rem = col & 1023;
                    int h = rem >> 6, d = rem & 63;
                    int b = m >> 11, t = m & 2047;
                    if (which == 0) {
                        // fold softmax scale AND log2(e): 0.125 * 1.4426950408889634
                        q[((size_t)((b * HH + h) * TT + t)) * DHH + d] = f2b(val * 0.18033688011112042f);
                    } else if (which == 1) {
                        k[((size_t)((b * HH + h) * TT + t)) * DHH + d] = f2b(val);
                    } else {
                        vt[((size_t)((b * HH + h) * DHH + d)) * TT + t] = f2b(val);
                    }
                } else {
                    outf[(size_t)m * N + col] = val;
                }
            }
        }
    }
}

// ---------------- flash attention, swapped-operand 32x32 ----------------
// grid 512 blocks (XCD-swizzled), 4 waves/block, each wave owns 32 q-rows.
// KVBLK=128 staged per barrier (K[128][64] + Vt[64][128] = 32KB, dbuf = 64KB LDS);
// the verified 64-key math body runs twice per staged tile -> half the barriers,
// vmcnt drains, and staging overhead vs KVBLK=64.
// S^T = K*Q^T (lane owns one q-row), softmax per-lane scalar state,
// P -> B-frag via cvt_pk_bf16 + permlane32_swap, O^T = V^T * P^T.
__global__ __launch_bounds__(256) void attn(
    const unsigned short* __restrict__ qb,
    const unsigned short* __restrict__ kb,
    const unsigned short* __restrict__ vtb,
    unsigned short* __restrict__ ob)
{
    extern __shared__ char lds[];        // 2 bufs x (K 16KB | Vt 16KB) = 64KB

    int tid = threadIdx.x;
    int l = tid & 63, w = tid >> 6;
    int hi = l >> 5, c = l & 31;

    // XCD swizzle: 4 heads' K/V per XCD L2
    int lin = blockIdx.y * gridDim.x + blockIdx.x;       // 0..511
    int swz = (lin & 7) * 64 + (lin >> 3);
    int bh = swz >> 4;
    int qrow = (swz & 15) * 128 + w * 32 + c;

    // Q as B-fragments: col = qrow (lane&31), k = d = kd*16 + hi*8 + j
    bf16x8 qf[4];
    const unsigned short* qg = qb + ((size_t)bh * TT + qrow) * DHH;
#pragma unroll
    for (int kd = 0; kd < 4; ++kd)
        qf[kd] = *(const bf16x8*)(qg + kd * 16 + hi * 8);

    f32x16 oa0 = {}, oa1 = {};
    float m = -1e30f, lsum = 0.f;

    const char* kgl = (const char*)(kb + (size_t)bh * TT * DHH);
    const char* vgl = (const char*)(vtb + (size_t)bh * DHH * TT);

    // stage K [128 key][64 d] (rows 128B) and Vt [64 d][128 key] (rows 256B),
    // XOR-swizzled (f(row) = (row&7)<<4) via pre-swizzled global source.
    auto stage = [&](int buf, int kt0) {
        char* base = lds + buf * 32768;
#pragma unroll
        for (int r = 0; r < 4; ++r) {
            int p = r * 4096 + tid * 16;
            {   // K: rw = p>>7 (0..127), qq = p&127
                int rw = p >> 7, qq = p & 127;
                int sw = qq ^ ((rw & 7) << 4);
                gl_lds16(kgl + (size_t)(kt0 + rw) * 128 + sw, base + p);
            }
            {   // Vt: rw = p>>8 (0..63), qq = p&255 (f only touches bits 4-6)
                int rw = p >> 8, qq = p & 255;
                int sw = qq ^ ((rw & 7) << 4);
                gl_lds16(vgl + (size_t)rw * (TT * 2) + kt0 * 2 + sw, base + 16384 + p);
            }
        }
    };

    stage(0, 0);
    __syncthreads();
    int cur = 0;

    for (int kt0 = 0; kt0 < TT; kt0 += 128) {
        if (kt0 + 128 < TT) stage(cur ^ 1, kt0 + 128);   // prefetch next 128-key tile
        const char* Ksb = lds + cur * 32768;
        const char* Vsb = Ksb + 16384;

#pragma unroll
        for (int kbi = 0; kbi < 2; ++kbi) {
            // ---- 64-key sub-body (keys kt0 + kbi*64 ...) ----
            // S^T = K * Q^T : D rows = key, cols = q-row (lane&31)
            f32x16 s0 = {}, s1 = {};
            __builtin_amdgcn_s_setprio(1);
#pragma unroll
            for (int kd = 0; kd < 4; ++kd) {
                int cb = (kd * 16 + hi * 8) * 2;
                int xr = cb ^ ((c & 7) << 4);
                bf16x8 kf0 = *(const bf16x8*)(Ksb + (kbi * 64 + c) * 128 + xr);
                bf16x8 kf1 = *(const bf16x8*)(Ksb + (kbi * 64 + 32 + c) * 128 + xr);
                s0 = mfma32(kf0, qf[kd], s0);
                s1 = mfma32(kf1, qf[kd], s1);
            }
            __builtin_amdgcn_s_setprio(0);

            // online softmax (log2 domain); tree max
            float mx[16];
#pragma unroll
            for (int r = 0; r < 16; ++r) mx[r] = fmaxf(s0[r], s1[r]);
#pragma unroll
            for (int d = 8; d >= 1; d >>= 1)
#pragma unroll
                for (int r = 0; r < d; ++r) mx[r] = fmaxf(mx[r], mx[r + d]);
            float tm = fmaxf(mx[0], __shfl_xor(mx[0], 32, 64));

            float nm = fmaxf(m, tm);
            if (!__all(nm - m <= 8.f)) {        // T13: defer rescale unless max grew >8
                float corr = fexp2(m - nm);
                lsum *= corr;
#pragma unroll
                for (int r = 0; r < 16; ++r) { oa0[r] *= corr; oa1[r] *= corr; }
                m = nm;
            }

            float p4[4] = {0.f, 0.f, 0.f, 0.f};
#pragma unroll
            for (int r = 0; r < 16; ++r) { s0[r] = fexp2(s0[r] - m); p4[r & 3] += s0[r]; }
#pragma unroll
            for (int r = 0; r < 16; ++r) { s1[r] = fexp2(s1[r] - m); p4[r & 3] += s1[r]; }
            float psum = (p4[0] + p4[1]) + (p4[2] + p4[3]);
            psum += __shfl_xor(psum, 32);
            lsum += psum;

            // P^T -> B-fragments: cvt_pk + permlane32_swap
            u32x4 pf0, pf1, pf2, pf3;
#define MKFRAG(sv, base_, dst) { \
            unsigned int c0 = pkbf(sv[base_+0], sv[base_+1]); \
            unsigned int c1 = pkbf(sv[base_+2], sv[base_+3]); \
            unsigned int c2 = pkbf(sv[base_+4], sv[base_+5]); \
            unsigned int c3 = pkbf(sv[base_+6], sv[base_+7]); \
            pl32swap(c0, c2); pl32swap(c1, c3); \
            dst[0] = c0; dst[1] = c1; dst[2] = c2; dst[3] = c3; }
            MKFRAG(s0, 0, pf0)
            MKFRAG(s0, 8, pf1)
            MKFRAG(s1, 0, pf2)
            MKFRAG(s1, 8, pf3)
#undef MKFRAG

            // O^T += V^T * P^T : A = Vt (row = d, 256B rows), B = P
            __builtin_amdgcn_s_setprio(1);
#define PVSTEP(kc, pf) { \
            int cb = kbi * 128 + (kc * 16 + hi * 8) * 2; \
            int xr = ((c & 7) << 4); \
            bf16x8 vf0 = *(const bf16x8*)(Vsb + c * 256 + (cb ^ xr)); \
            bf16x8 vf1 = *(const bf16x8*)(Vsb + (32 + c) * 256 + (cb ^ xr)); \
            bf16x8 ph = u2h(pf); \
            oa0 = mfma32(vf0, ph, oa0); \
            oa1 = mfma32(vf1, ph, oa1); }
            PVSTEP(0, pf0)
            PVSTEP(1, pf1)
            PVSTEP(2, pf2)
            PVSTEP(3, pf3)
#undef PVSTEP
            __builtin_amdgcn_s_setprio(0);
        }

        __syncthreads();                 // prefetch landed + all reads done
        cur ^= 1;
    }

    // normalize, write O^T back as O[b, t, h*64 + d]
    float rn = 1.0f / lsum;
    int b = bh >> 4, h = bh & 15;
    unsigned short* obase = ob + ((size_t)(b * TT + qrow)) * DD + h * 64;
#pragma unroll
    for (int g = 0; g < 4; ++g) {
        u16x4 o0, o1;
#pragma unroll
        for (int e = 0; e < 4; ++e) {
            o0[e] = f2b(oa0[g * 4 + e] * rn);
            o1[e] = f2b(oa1[g * 4 + e] * rn);
        }
        *(u16x4*)(obase + 8 * g + 4 * hi)      = o0;   // d = e + 8g + 4hi (db=0)
        *(u16x4*)(obase + 32 + 8 * g + 4 * hi) = o1;   // db=1
    }
}

// ---------------- launcher ----------------
extern "C" void kernel_launch(void* const* d_in, const int* in_sizes, int n_in,
                              void* d_out, int out_size, void* d_ws, size_t ws_size,
                              hipStream_t stream) {
    const float* x    = (const float*)d_in[0];
    const float* Wqkv = (const float*)d_in[1];
    const float* bqkv = (const float*)d_in[2];
    const float* Wo   = (const float*)d_in[3];
    const float* bo   = (const float*)d_in[4];
    float* out = (float*)d_out;

    unsigned short* xb  = (unsigned short*)d_ws;        // [4096,1024]
    unsigned short* wqb = xb  + 4096 * 1024;            // [3072,1024]
    unsigned short* wob = wqb + 3072 * 1024;            // [1024,1024]
    unsigned short* q   = wob + 1024 * 1024;            // [B,H,T,DH]
    unsigned short* k   = q   + 2 * 16 * 2048 * 64;     // [B,H,T,DH]
    unsigned short* vt  = k   + 2 * 16 * 2048 * 64;     // [B,H,DH,T]
    unsigned short* ob  = vt  + 2 * 16 * 2048 * 64;     // [4096,1024]

    f2b_kernel<<<dim3(1024), dim3(256), 0, stream>>>(x,    xb,  4096 * 1024 / 4);
    f2b_kernel<<<dim3(768),  dim3(256), 0, stream>>>(Wqkv, wqb, 3072 * 1024 / 4);
    f2b_kernel<<<dim3(256),  dim3(256), 0, stream>>>(Wo,   wob, 1024 * 1024 / 4);

    // QKV projection: M=4096, N=3072, K=1024
    gemm_bt<128, 0><<<dim3(24, 32), dim3(256), 0, stream>>>(xb, wqb, bqkv, 3072, 1024,
                                                            q, k, vt, nullptr);
    // attention: 512 blocks, 4 waves each, 64KB dynamic LDS
    attn<<<dim3(16, 32), dim3(256), 65536, stream>>>(q, k, vt, ob);

    // output projection: M=4096, N=1024, K=1024 (BN=64 -> 512 blocks)
    gemm_bt<64, 1><<<dim3(16, 32), dim3(256), 0, stream>>>(ob, wob, bo, 1024, 1024,
                                                           nullptr, nullptr, nullptr, out);
}

// Round 5
// 123.764 us; speedup vs baseline: 1.0607x; 1.0607x over previous
//
#include <hip/hip_runtime.h>

// Problem constants: B=2, T=2048, D=1024, H=16, DH=64
#define TT 2048
#define DD 1024
#define HH 16
#define DHH 64

typedef __attribute__((ext_vector_type(4)))  float  f32x4;
typedef __attribute__((ext_vector_type(16))) float  f32x16;
typedef __attribute__((ext_vector_type(8)))  short  bf16x8;   // 8 bf16 in 4 VGPRs
typedef __attribute__((ext_vector_type(4)))  float  f4;
typedef __attribute__((ext_vector_type(4)))  unsigned short u16x4;
typedef __attribute__((ext_vector_type(4)))  unsigned int   u32x4;

// fp32 -> bf16 round-to-nearest-even
__device__ __forceinline__ unsigned short f2b(float f) {
    union { float f; unsigned int u; } v; v.f = f;
    unsigned int r = v.u + 0x7fffu + ((v.u >> 16) & 1u);
    return (unsigned short)(r >> 16);
}

// async global->LDS, 16B per lane; LDS dest must be wave-uniform base + lane*16
__device__ __forceinline__ void gl_lds16(const void* g, void* l) {
    __builtin_amdgcn_global_load_lds(
        (const __attribute__((address_space(1))) unsigned int*)g,
        (__attribute__((address_space(3))) unsigned int*)l, 16, 0, 0);
}

__device__ __forceinline__ f32x16 mfma32(bf16x8 a, bf16x8 b, f32x16 c) {
    return __builtin_amdgcn_mfma_f32_32x32x16_bf16(a, b, c, 0, 0, 0);
}

// 2^x via v_exp_f32
__device__ __forceinline__ float fexp2(float x) {
    float r; asm("v_exp_f32 %0, %1" : "=v"(r) : "v"(x)); return r;
}

// pack two f32 -> u32 of 2 bf16 (lo = a, hi = b)
__device__ __forceinline__ unsigned int pkbf(float a, float b) {
    unsigned int r;
    asm("v_cvt_pk_bf16_f32 %0, %1, %2" : "=v"(r) : "v"(a), "v"(b));
    return r;
}

// v_permlane32_swap_b32: a'[32+i]=b[i]; b'[i]=a[32+i]
__device__ __forceinline__ void pl32swap(unsigned int& a, unsigned int& b) {
    asm("v_permlane32_swap_b32 %0, %1" : "+v"(a), "+v"(b));
}

__device__ __forceinline__ bf16x8 u2h(u32x4 u) {
    union { u32x4 u; bf16x8 h; } x; x.u = u; return x.h;
}

// ---------------- fp32 -> bf16 conversion (vectorized) ----------------
__global__ void f2b_kernel(const float* __restrict__ s, unsigned short* __restrict__ d, int n4) {
    int i = blockIdx.x * blockDim.x + threadIdx.x;
    int stride = gridDim.x * blockDim.x;
    for (; i < n4; i += stride) {
        f4 v = ((const f4*)s)[i];
        u16x4 o;
        o[0] = f2b(v[0]); o[1] = f2b(v[1]); o[2] = f2b(v[2]); o[3] = f2b(v[3]);
        ((u16x4*)d)[i] = o;
    }
}

// ---------------- GEMM: C[M,N] = A[M,K] * Bm[N,K]^T + bias ----------------
// 128 x BN tile, 4 waves (2x2), 2-phase double-buffered LDS staging.
// MODE 0 (BN=128): QKV epilogue -> q scaled by 0.125*log2e, k [B,H,T,DH], vt [B,H,DH,T]
// MODE 1 (BN=64):  fp32 out + bias (final projection; BN=64 -> 512 blocks)
template<int BN, int MODE>
__global__ __launch_bounds__(256) void gemm_bt(
    const unsigned short* __restrict__ A, const unsigned short* __restrict__ Bm,
    const float* __restrict__ bias, int N, int K,
    unsigned short* __restrict__ q, unsigned short* __restrict__ k,
    unsigned short* __restrict__ vt, float* __restrict__ outf)
{
    constexpr int NB  = BN / 32;        // B-frags per wave
    constexpr int ASZ = 128 * 32;       // shorts per A tile
    constexpr int BSZ = BN * 32;        // shorts per B tile
    __shared__ unsigned short lds[2 * (ASZ + BSZ)];

    int tid = threadIdx.x;
    int l = tid & 63, w = tid >> 6;
    int wr = w >> 1, wc = w & 1;
    int lr = l & 15, lk = (l >> 4) * 8;
    int bm = blockIdx.y, bn = blockIdx.x;

    f32x4 acc[4][NB] = {};

    const unsigned short* Ag = A + (size_t)(bm * 128) * K;
    const unsigned short* Bg = Bm + (size_t)(bn * BN) * K;

    auto stage = [&](int buf, int k0) {
        unsigned short* As = lds + buf * (ASZ + BSZ);
        unsigned short* Bs = As + ASZ;
#pragma unroll
        for (int r = 0; r < 2; ++r) {
            int e = r * 256 + tid;
            int row = e >> 2, kc = (e & 3) * 8;
            gl_lds16(Ag + (size_t)row * K + k0 + kc, &As[e * 8]);
        }
#pragma unroll
        for (int r = 0; r < BN / 64; ++r) {
            int e = r * 256 + tid;
            int row = e >> 2, kc = (e & 3) * 8;
            gl_lds16(Bg + (size_t)row * K + k0 + kc, &Bs[e * 8]);
        }
    };

    stage(0, 0);
    __syncthreads();
    int cur = 0;
    for (int k0 = 0; k0 < K; k0 += 32) {
        if (k0 + 32 < K) stage(cur ^ 1, k0 + 32);   // prefetch next tile
        const unsigned short* As = lds + cur * (ASZ + BSZ);
        const unsigned short* Bs = As + ASZ;
        bf16x8 a[4], b[NB];
#pragma unroll
        for (int i = 0; i < 4; ++i)
            a[i] = *(const bf16x8*)&As[(wr * 64 + i * 16 + lr) * 32 + lk];
#pragma unroll
        for (int j = 0; j < NB; ++j)
            b[j] = *(const bf16x8*)&Bs[(wc * (BN / 2) + j * 16 + lr) * 32 + lk];
        __builtin_amdgcn_s_setprio(1);
#pragma unroll
        for (int i = 0; i < 4; ++i)
#pragma unroll
            for (int j = 0; j < NB; ++j)
                acc[i][j] = __builtin_amdgcn_mfma_f32_16x16x32_bf16(a[i], b[j], acc[i][j], 0, 0, 0);
        __builtin_amdgcn_s_setprio(0);
        __syncthreads();
        cur ^= 1;
    }

#pragma unroll
    for (int i = 0; i < 4; ++i) {
#pragma unroll
        for (int j = 0; j < NB; ++j) {
            int row0 = bm * 128 + wr * 64 + i * 16 + (l >> 4) * 4;
            int col  = bn * BN + wc * (BN / 2) + j * 16 + (l & 15);
            float bv = bias[col];
#pragma unroll
            for (int r = 0; r < 4; ++r) {
                float val = acc[i][j][r] + bv;
                int m = row0 + r;
                if (MODE == 0) {
                    int which = col >> 10, rem = col & 1023;
                    int h = rem >> 6, d = rem & 63;
                    int b = m >> 11, t = m & 2047;
                    if (which == 0) {
                        // fold softmax scale AND log2(e): 0.125 * 1.4426950408889634
                        q[((size_t)((b * HH + h) * TT + t)) * DHH + d] = f2b(val * 0.18033688011112042f);
                    } else if (which == 1) {
                        k[((size_t)((b * HH + h) * TT + t)) * DHH + d] = f2b(val);
                    } else {
                        vt[((size_t)((b * HH + h) * DHH + d)) * TT + t] = f2b(val);
                    }
                } else {
                    outf[(size_t)m * N + col] = val;
                }
            }
        }
    }
}

// ---------------- flash attention: split-K, swapped-operand 32x32 ----------------
// grid 512 blocks (XCD-swizzled), 8 waves = 2 key-groups x 4 waves.
// Group g handles keys [g*1024, g*1024+1024) over the block's 128 q-rows;
// each wave owns 32 q-rows. 4096 waves total -> 4 waves/SIMD (2x prior occupancy).
// Per group: single-buffered KVBLK=64 staging (r2 structure, the measured best).
// S^T = K*Q^T (lane owns one q-row), per-lane scalar softmax state,
// P -> B-frag via cvt_pk_bf16 + permlane32_swap, O^T = V^T * P^T.
// End: group 1 publishes (m,l,O) via lane-major LDS; group 0 merges + writes.
__global__ __launch_bounds__(512, 4) void attn(
    const unsigned short* __restrict__ qb,
    const unsigned short* __restrict__ kb,
    const unsigned short* __restrict__ vtb,
    unsigned short* __restrict__ ob)
{
    extern __shared__ char lds[];   // staging: [2 groups][K 8KB | V 8KB] = 32KB
                                    // merge overlay: Om 32KB + ml 2KB = 34KB

    int tid = threadIdx.x;
    int l = tid & 63, w = tid >> 6;      // w 0..7
    int g = w >> 2, wg = w & 3;          // key-group, wave-in-group
    int hi = l >> 5, c = l & 31;
    int tig = tid & 255;                 // thread-in-group

    // XCD swizzle: 4 heads' K/V per XCD L2
    int lin = blockIdx.x;                // 0..511
    int swz = (lin & 7) * 64 + (lin >> 3);
    int bh = swz >> 4;
    int qrow = (swz & 15) * 128 + wg * 32 + c;

    // Q as B-fragments: col = qrow (lane&31), k = d = kd*16 + hi*8 + j
    bf16x8 qf[4];
    const unsigned short* qg = qb + ((size_t)bh * TT + qrow) * DHH;
#pragma unroll
    for (int kd = 0; kd < 4; ++kd)
        qf[kd] = *(const bf16x8*)(qg + kd * 16 + hi * 8);

    f32x16 oa0 = {}, oa1 = {};
    float m = -1e30f, lsum = 0.f;

    // group key-range base folded into pointers
    const char* kgl = (const char*)(kb + (size_t)bh * TT * DHH) + (size_t)g * 1024 * 128;
    const char* vgl = (const char*)(vtb + (size_t)bh * DHH * TT) + (size_t)g * 1024 * 2;
    char* base = lds + g * 16384;        // this group's staging slice

    for (int kt0 = 0; kt0 < 1024; kt0 += 64) {
        // stage K [64 key][64 d] and Vt [64 d][64 key]; rows 128B, XOR-swizzled
        // via pre-swizzled global source (gl_lds dest must stay linear)
#pragma unroll
        for (int r = 0; r < 2; ++r) {
            int p = r * 4096 + tig * 16;
            int rw = p >> 7, qq = p & 127;
            int sw = qq ^ ((rw & 7) << 4);
            gl_lds16(kgl + (size_t)(kt0 + rw) * 128 + sw, base + p);
            gl_lds16(vgl + (size_t)rw * (TT * 2) + kt0 * 2 + sw, base + 8192 + p);
        }
        __syncthreads();
        const char* Ksb = base;
        const char* Vsb = base + 8192;

        // S^T = K * Q^T : D rows = key, cols = q-row (lane&31)
        f32x16 s0 = {}, s1 = {};
        __builtin_amdgcn_s_setprio(1);
#pragma unroll
        for (int kd = 0; kd < 4; ++kd) {
            int cb = (kd * 16 + hi * 8) * 2;
            int xr = cb ^ ((c & 7) << 4);
            bf16x8 kf0 = *(const bf16x8*)(Ksb + c * 128 + xr);
            bf16x8 kf1 = *(const bf16x8*)(Ksb + (32 + c) * 128 + xr);
            s0 = mfma32(kf0, qf[kd], s0);
            s1 = mfma32(kf1, qf[kd], s1);
        }
        __builtin_amdgcn_s_setprio(0);

        // online softmax (log2 domain); tree max
        float mx[16];
#pragma unroll
        for (int r = 0; r < 16; ++r) mx[r] = fmaxf(s0[r], s1[r]);
#pragma unroll
        for (int d = 8; d >= 1; d >>= 1)
#pragma unroll
            for (int r = 0; r < d; ++r) mx[r] = fmaxf(mx[r], mx[r + d]);
        float tm = fmaxf(mx[0], __shfl_xor(mx[0], 32, 64));

        float nm = fmaxf(m, tm);
        if (!__all(nm - m <= 8.f)) {        // T13: defer rescale unless max grew >8
            float corr = fexp2(m - nm);
            lsum *= corr;
#pragma unroll
            for (int r = 0; r < 16; ++r) { oa0[r] *= corr; oa1[r] *= corr; }
            m = nm;
        }

        float p4[4] = {0.f, 0.f, 0.f, 0.f};
#pragma unroll
        for (int r = 0; r < 16; ++r) { s0[r] = fexp2(s0[r] - m); p4[r & 3] += s0[r]; }
#pragma unroll
        for (int r = 0; r < 16; ++r) { s1[r] = fexp2(s1[r] - m); p4[r & 3] += s1[r]; }
        float psum = (p4[0] + p4[1]) + (p4[2] + p4[3]);
        psum += __shfl_xor(psum, 32);
        lsum += psum;

        // P^T -> B-fragments: cvt_pk + permlane32_swap
        u32x4 pf0, pf1, pf2, pf3;
#define MKFRAG(sv, base_, dst) { \
        unsigned int c0 = pkbf(sv[base_+0], sv[base_+1]); \
        unsigned int c1 = pkbf(sv[base_+2], sv[base_+3]); \
        unsigned int c2 = pkbf(sv[base_+4], sv[base_+5]); \
        unsigned int c3 = pkbf(sv[base_+6], sv[base_+7]); \
        pl32swap(c0, c2); pl32swap(c1, c3); \
        dst[0] = c0; dst[1] = c1; dst[2] = c2; dst[3] = c3; }
        MKFRAG(s0, 0, pf0)
        MKFRAG(s0, 8, pf1)
        MKFRAG(s1, 0, pf2)
        MKFRAG(s1, 8, pf3)
#undef MKFRAG

        // O^T += V^T * P^T : A = Vt (row = d), B = P (col = q-row)
        __builtin_amdgcn_s_setprio(1);
#define PVSTEP(kc, pf) { \
        int cb = (kc * 16 + hi * 8) * 2; \
        int xr = ((c & 7) << 4); \
        bf16x8 vf0 = *(const bf16x8*)(Vsb + c * 128 + (cb ^ xr)); \
        bf16x8 vf1 = *(const bf16x8*)(Vsb + (32 + c) * 128 + (cb ^ xr)); \
        bf16x8 ph = u2h(pf); \
        oa0 = mfma32(vf0, ph, oa0); \
        oa1 = mfma32(vf1, ph, oa1); }
        PVSTEP(0, pf0)
        PVSTEP(1, pf1)
        PVSTEP(2, pf2)
        PVSTEP(3, pf3)
#undef PVSTEP
        __builtin_amdgcn_s_setprio(0);

        __syncthreads();                 // all reads done before restage
    }

    // ---- merge the two key-groups' (m, l, O) ----
    // lane-major overlay: Om[wg][r 0..31][lane] floats, ml[wg][0..1][lane]
    float* Om = (float*)lds;                       // 4*32*64*4 = 32 KB
    float* ml = (float*)(lds + 32768);             // 4*2*64*4  = 2 KB
    if (g == 1) {
        float* o = Om + wg * 2048 + l;
#pragma unroll
        for (int r = 0; r < 16; ++r) o[r * 64]        = oa0[r];
#pragma unroll
        for (int r = 0; r < 16; ++r) o[(16 + r) * 64] = oa1[r];
        ml[wg * 128 + l]      = m;
        ml[wg * 128 + 64 + l] = lsum;
    }
    __syncthreads();
    if (g == 1) return;

    float m2 = ml[wg * 128 + l];
    float l2 = ml[wg * 128 + 64 + l];
    float M  = fmaxf(m, m2);
    float a1 = fexp2(m - M), a2 = fexp2(m2 - M);
    float L  = lsum * a1 + l2 * a2;
    float rn = 1.0f / L;
    const float* o2 = Om + wg * 2048 + l;

    // normalize, write O^T back as O[b, t, h*64 + d]
    int b = bh >> 4, h = bh & 15;
    unsigned short* obase = ob + ((size_t)(b * TT + qrow)) * DD + h * 64;
#pragma unroll
    for (int gq = 0; gq < 4; ++gq) {
        u16x4 o0, o1;
#pragma unroll
        for (int e = 0; e < 4; ++e) {
            int r = gq * 4 + e;
            o0[e] = f2b((oa0[r] * a1 + o2[r * 64] * a2) * rn);
            o1[e] = f2b((oa1[r] * a1 + o2[(16 + r) * 64] * a2) * rn);
        }
        *(u16x4*)(obase + 8 * gq + 4 * hi)      = o0;   // d = e + 8gq + 4hi (db=0)
        *(u16x4*)(obase + 32 + 8 * gq + 4 * hi) = o1;   // db=1
    }
}

// ---------------- launcher ----------------
extern "C" void kernel_launch(void* const* d_in, const int* in_sizes, int n_in,
                              void* d_out, int out_size, void* d_ws, size_t ws_size,
                              hipStream_t stream) {
    const float* x    = (const float*)d_in[0];
    const float* Wqkv = (const float*)d_in[1];
    const float* bqkv = (const float*)d_in[2];
    const float* Wo   = (const float*)d_in[3];
    const float* bo   = (const float*)d_in[4];
    float* out = (float*)d_out;

    unsigned short* xb  = (unsigned short*)d_ws;        // [4096,1024]
    unsigned short* wqb = xb  + 4096 * 1024;            // [3072,1024]
    unsigned short* wob = wqb + 3072 * 1024;            // [1024,1024]
    unsigned short* q   = wob + 1024 * 1024;            // [B,H,T,DH]
    unsigned short* k   = q   + 2 * 16 * 2048 * 64;     // [B,H,T,DH]
    unsigned short* vt  = k   + 2 * 16 * 2048 * 64;     // [B,H,DH,T]
    unsigned short* ob  = vt  + 2 * 16 * 2048 * 64;     // [4096,1024]

    f2b_kernel<<<dim3(1024), dim3(256), 0, stream>>>(x,    xb,  4096 * 1024 / 4);
    f2b_kernel<<<dim3(768),  dim3(256), 0, stream>>>(Wqkv, wqb, 3072 * 1024 / 4);
    f2b_kernel<<<dim3(256),  dim3(256), 0, stream>>>(Wo,   wob, 1024 * 1024 / 4);

    // QKV projection: M=4096, N=3072, K=1024
    gemm_bt<128, 0><<<dim3(24, 32), dim3(256), 0, stream>>>(xb, wqb, bqkv, 3072, 1024,
                                                            q, k, vt, nullptr);
    // attention: 512 blocks x 512 threads (2 key-groups), 34 KB dynamic LDS
    attn<<<dim3(512), dim3(512), 34816, stream>>>(q, k, vt, ob);

    // output projection: M=4096, N=1024, K=1024 (BN=64 -> 512 blocks)
    gemm_bt<64, 1><<<dim3(16, 32), dim3(256), 0, stream>>>(ob, wob, bo, 1024, 1024,
                                                           nullptr, nullptr, nullptr, out);
}

// Round 7
// 120.053 us; speedup vs baseline: 1.0935x; 1.0309x over previous
//
#include <hip/hip_runtime.h>

// Problem constants: B=2, T=2048, D=1024, H=16, DH=64
#define TT 2048
#define DD 1024
#define HH 16
#define DHH 64

typedef __attribute__((ext_vector_type(4)))  float  f32x4;
typedef __attribute__((ext_vector_type(16))) float  f32x16;
typedef __attribute__((ext_vector_type(8)))  short  bf16x8;   // 8 bf16 in 4 VGPRs
typedef __attribute__((ext_vector_type(4)))  float  f4;
typedef __attribute__((ext_vector_type(4)))  unsigned short u16x4;
typedef __attribute__((ext_vector_type(4)))  unsigned int   u32x4;

// fp32 -> bf16 round-to-nearest-even
__device__ __forceinline__ unsigned short f2b(float f) {
    union { float f; unsigned int u; } v; v.f = f;
    unsigned int r = v.u + 0x7fffu + ((v.u >> 16) & 1u);
    return (unsigned short)(r >> 16);
}

// async global->LDS, 16B per lane; LDS dest must be wave-uniform base + lane*16
__device__ __forceinline__ void gl_lds16(const void* g, void* l) {
    __builtin_amdgcn_global_load_lds(
        (const __attribute__((address_space(1))) unsigned int*)g,
        (__attribute__((address_space(3))) unsigned int*)l, 16, 0, 0);
}

__device__ __forceinline__ f32x16 mfma32(bf16x8 a, bf16x8 b, f32x16 c) {
    return __builtin_amdgcn_mfma_f32_32x32x16_bf16(a, b, c, 0, 0, 0);
}

// 2^x via v_exp_f32
__device__ __forceinline__ float fexp2(float x) {
    float r; asm("v_exp_f32 %0, %1" : "=v"(r) : "v"(x)); return r;
}

// pack two f32 -> u32 of 2 bf16 (lo = a, hi = b)
__device__ __forceinline__ unsigned int pkbf(float a, float b) {
    unsigned int r;
    asm("v_cvt_pk_bf16_f32 %0, %1, %2" : "=v"(r) : "v"(a), "v"(b));
    return r;
}

// v_permlane32_swap_b32: a'[32+i]=b[i]; b'[i]=a[32+i]
__device__ __forceinline__ void pl32swap(unsigned int& a, unsigned int& b) {
    asm("v_permlane32_swap_b32 %0, %1" : "+v"(a), "+v"(b));
}

__device__ __forceinline__ bf16x8 u2h(u32x4 u) {
    union { u32x4 u; bf16x8 h; } x; x.u = u; return x.h;
}

// ---------------- fp32 -> bf16 conversion: one kernel for all three inputs ----
// Destinations xb|wqb|wob are contiguous in ws; flat f4 index picks the source.
// sizes (f4 units): x 1048576, Wqkv 786432 (cum 1835008), Wo 262144 (tot 2097152)
__global__ void f2b3_kernel(const float* __restrict__ x, const float* __restrict__ wq,
                            const float* __restrict__ wo, unsigned short* __restrict__ d) {
    int i = blockIdx.x * blockDim.x + threadIdx.x;    // grid exactly 2097152 threads
    const float* s; int off;
    if (i < 1048576)      { s = x;  off = i; }
    else if (i < 1835008) { s = wq; off = i - 1048576; }
    else                  { s = wo; off = i - 1835008; }
    f4 v = ((const f4*)s)[off];
    u16x4 o;
    o[0] = f2b(v[0]); o[1] = f2b(v[1]); o[2] = f2b(v[2]); o[3] = f2b(v[3]);
    ((u16x4*)d)[i] = o;
}

// ---------------- GEMM: C[M,N] = A[M,K] * Bm[N,K]^T + bias ----------------
// 128 x BN tile, 4 waves (2x2), 2-phase double-buffered LDS staging.
// MODE 0 (BN=128): QKV epilogue -> q scaled by 0.125*log2e, k [B,H,T,DH], vt [B,H,DH,T]
// MODE 1 (BN=64):  fp32 out + bias (final projection; BN=64 -> 512 blocks)
template<int BN, int MODE>
__global__ __launch_bounds__(256) void gemm_bt(
    const unsigned short* __restrict__ A, const unsigned short* __restrict__ Bm,
    const float* __restrict__ bias, int N, int K,
    unsigned short* __restrict__ q, unsigned short* __restrict__ k,
    unsigned short* __restrict__ vt, float* __restrict__ outf)
{
    constexpr int NB  = BN / 32;        // B-frags per wave
    constexpr int ASZ = 128 * 32;       // shorts per A tile
    constexpr int BSZ = BN * 32;        // shorts per B tile
    __shared__ unsigned short lds[2 * (ASZ + BSZ)];

    int tid = threadIdx.x;
    int l = tid & 63, w = tid >> 6;
    int wr = w >> 1, wc = w & 1;
    int lr = l & 15, lk = (l >> 4) * 8;
    int bm = blockIdx.y, bn = blockIdx.x;

    f32x4 acc[4][NB] = {};

    const unsigned short* Ag = A + (size_t)(bm * 128) * K;
    const unsigned short* Bg = Bm + (size_t)(bn * BN) * K;

    auto stage = [&](int buf, int k0) {
        unsigned short* As = lds + buf * (ASZ + BSZ);
        unsigned short* Bs = As + ASZ;
#pragma unroll
        for (int r = 0; r < 2; ++r) {
            int e = r * 256 + tid;
            int row = e >> 2, kc = (e & 3) * 8;
            gl_lds16(Ag + (size_t)row * K + k0 + kc, &As[e * 8]);
        }
#pragma unroll
        for (int r = 0; r < BN / 64; ++r) {
            int e = r * 256 + tid;
            int row = e >> 2, kc = (e & 3) * 8;
            gl_lds16(Bg + (size_t)row * K + k0 + kc, &Bs[e * 8]);
        }
    };

    stage(0, 0);
    __syncthreads();
    int cur = 0;
    for (int k0 = 0; k0 < K; k0 += 32) {
        if (k0 + 32 < K) stage(cur ^ 1, k0 + 32);   // prefetch next tile
        const unsigned short* As = lds + cur * (ASZ + BSZ);
        const unsigned short* Bs = As + ASZ;
        bf16x8 a[4], b[NB];
#pragma unroll
        for (int i = 0; i < 4; ++i)
            a[i] = *(const bf16x8*)&As[(wr * 64 + i * 16 + lr) * 32 + lk];
#pragma unroll
        for (int j = 0; j < NB; ++j)
            b[j] = *(const bf16x8*)&Bs[(wc * (BN / 2) + j * 16 + lr) * 32 + lk];
        __builtin_amdgcn_s_setprio(1);
#pragma unroll
        for (int i = 0; i < 4; ++i)
#pragma unroll
            for (int j = 0; j < NB; ++j)
                acc[i][j] = __builtin_amdgcn_mfma_f32_16x16x32_bf16(a[i], b[j], acc[i][j], 0, 0, 0);
        __builtin_amdgcn_s_setprio(0);
        __syncthreads();
        cur ^= 1;
    }

#pragma unroll
    for (int i = 0; i < 4; ++i) {
#pragma unroll
        for (int j = 0; j < NB; ++j) {
            int row0 = bm * 128 + wr * 64 + i * 16 + (l >> 4) * 4;
            int col  = bn * BN + wc * (BN / 2) + j * 16 + (l & 15);
            float bv = bias[col];
#pragma unroll
            for (int r = 0; r < 4; ++r) {
                float val = acc[i][j][r] + bv;
                int m = row0 + r;
                if (MODE == 0) {
                    int which = col >> 10, rem = col & 1023;
                    int h = rem >> 6, d = rem & 63;
                    int b = m >> 11, t = m & 2047;
                    if (which == 0) {
                        // fold softmax scale AND log2(e): 0.125 * 1.4426950408889634
                        q[((size_t)((b * HH + h) * TT + t)) * DHH + d] = f2b(val * 0.18033688011112042f);
                    } else if (which == 1) {
                        k[((size_t)((b * HH + h) * TT + t)) * DHH + d] = f2b(val);
                    } else {
                        vt[((size_t)((b * HH + h) * DHH + d)) * TT + t] = f2b(val);
                    }
                } else {
                    outf[(size_t)m * N + col] = val;
                }
            }
        }
    }
}

// ---------------- flash attention: split-K, swapped-operand 32x32 ----------------
// grid 512 blocks (XCD-swizzled), 8 waves = 2 key-groups x 4 waves.
// Group g handles keys [g*1024, g*1024+1024) over the block's 128 q-rows;
// each wave owns 32 q-rows. 4096 waves total -> 4 waves/SIMD.
// Per group: single-buffered KVBLK=64 staging (r2/r5 structure, the measured best).
// S^T = K*Q^T (lane owns one q-row), per-lane scalar defer-max softmax state
// (PROVEN numerics — the r6 fixed-base variant failed accuracy 13x),
// P -> B-frag via cvt_pk_bf16 + permlane32_swap, O^T = V^T * P^T.
// End: group 1 publishes (m,l,O) via lane-major LDS; group 0 merges + writes.
__global__ __launch_bounds__(512, 4) void attn(
    const unsigned short* __restrict__ qb,
    const unsigned short* __restrict__ kb,
    const unsigned short* __restrict__ vtb,
    unsigned short* __restrict__ ob)
{
    extern __shared__ char lds[];   // staging: [2 groups][K 8KB | V 8KB] = 32KB
                                    // merge overlay: Om 32KB + ml 2KB = 34KB

    int tid = threadIdx.x;
    int l = tid & 63, w = tid >> 6;      // w 0..7
    int g = w >> 2, wg = w & 3;          // key-group, wave-in-group
    int hi = l >> 5, c = l & 31;
    int tig = tid & 255;                 // thread-in-group

    // XCD swizzle: 4 heads' K/V per XCD L2
    int lin = blockIdx.x;                // 0..511
    int swz = (lin & 7) * 64 + (lin >> 3);
    int bh = swz >> 4;
    int qrow = (swz & 15) * 128 + wg * 32 + c;

    // Q as B-fragments: col = qrow (lane&31), k = d = kd*16 + hi*8 + j
    bf16x8 qf[4];
    const unsigned short* qg = qb + ((size_t)bh * TT + qrow) * DHH;
#pragma unroll
    for (int kd = 0; kd < 4; ++kd)
        qf[kd] = *(const bf16x8*)(qg + kd * 16 + hi * 8);

    f32x16 oa0 = {}, oa1 = {};
    float m = -1e30f, lsum = 0.f;

    // group key-range base folded into pointers
    const char* kgl = (const char*)(kb + (size_t)bh * TT * DHH) + (size_t)g * 1024 * 128;
    const char* vgl = (const char*)(vtb + (size_t)bh * DHH * TT) + (size_t)g * 1024 * 2;
    char* base = lds + g * 16384;        // this group's staging slice

    for (int kt0 = 0; kt0 < 1024; kt0 += 64) {
        // stage K [64 key][64 d] and Vt [64 d][64 key]; rows 128B, XOR-swizzled
        // via pre-swizzled global source (gl_lds dest must stay linear)
#pragma unroll
        for (int r = 0; r < 2; ++r) {
            int p = r * 4096 + tig * 16;
            int rw = p >> 7, qq = p & 127;
            int sw = qq ^ ((rw & 7) << 4);
            gl_lds16(kgl + (size_t)(kt0 + rw) * 128 + sw, base + p);
            gl_lds16(vgl + (size_t)rw * (TT * 2) + kt0 * 2 + sw, base + 8192 + p);
        }
        __syncthreads();
        const char* Ksb = base;
        const char* Vsb = base + 8192;

        // S^T = K * Q^T : D rows = key, cols = q-row (lane&31)
        f32x16 s0 = {}, s1 = {};
        __builtin_amdgcn_s_setprio(1);
#pragma unroll
        for (int kd = 0; kd < 4; ++kd) {
            int cb = (kd * 16 + hi * 8) * 2;
            int xr = cb ^ ((c & 7) << 4);
            bf16x8 kf0 = *(const bf16x8*)(Ksb + c * 128 + xr);
            bf16x8 kf1 = *(const bf16x8*)(Ksb + (32 + c) * 128 + xr);
            s0 = mfma32(kf0, qf[kd], s0);
            s1 = mfma32(kf1, qf[kd], s1);
        }
        __builtin_amdgcn_s_setprio(0);

        // online softmax (log2 domain); max3-shaped tree (max is exactly
        // associative/commutative -> bitwise-identical to r5's tree)
        float mx[11];
#pragma unroll
        for (int r = 0; r < 10; ++r)
            mx[r] = fmaxf(fmaxf(s0[3 * r], s0[3 * r + 1]), s0[3 * r + 2]);  // r<6 hits s0[16..]? no: 3*5+2=17
        // careful: s0 has 16 entries; do 16+16 explicitly
        mx[0] = fmaxf(fmaxf(s0[0], s0[1]), s0[2]);
        mx[1] = fmaxf(fmaxf(s0[3], s0[4]), s0[5]);
        mx[2] = fmaxf(fmaxf(s0[6], s0[7]), s0[8]);
        mx[3] = fmaxf(fmaxf(s0[9], s0[10]), s0[11]);
        mx[4] = fmaxf(fmaxf(s0[12], s0[13]), s0[14]);
        mx[5] = fmaxf(fmaxf(s0[15], s1[0]), s1[1]);
        mx[6] = fmaxf(fmaxf(s1[2], s1[3]), s1[4]);
        mx[7] = fmaxf(fmaxf(s1[5], s1[6]), s1[7]);
        mx[8] = fmaxf(fmaxf(s1[8], s1[9]), s1[10]);
        mx[9] = fmaxf(fmaxf(s1[11], s1[12]), s1[13]);
        mx[10] = fmaxf(s1[14], s1[15]);
        float t0 = fmaxf(fmaxf(mx[0], mx[1]), mx[2]);
        float t1 = fmaxf(fmaxf(mx[3], mx[4]), mx[5]);
        float t2 = fmaxf(fmaxf(mx[6], mx[7]), mx[8]);
        float t3 = fmaxf(mx[9], mx[10]);
        float tm = fmaxf(fmaxf(t0, t1), fmaxf(t2, t3));
        tm = fmaxf(tm, __shfl_xor(tm, 32, 64));

        float nm = fmaxf(m, tm);
        if (!__all(nm - m <= 8.f)) {        // T13: defer rescale unless max grew >8
            float corr = fexp2(m - nm);
            lsum *= corr;
#pragma unroll
            for (int r = 0; r < 16; ++r) { oa0[r] *= corr; oa1[r] *= corr; }
            m = nm;
        }

        float p4[4] = {0.f, 0.f, 0.f, 0.f};
#pragma unroll
        for (int r = 0; r < 16; ++r) { s0[r] = fexp2(s0[r] - m); p4[r & 3] += s0[r]; }
#pragma unroll
        for (int r = 0; r < 16; ++r) { s1[r] = fexp2(s1[r] - m); p4[r & 3] += s1[r]; }
        float psum = (p4[0] + p4[1]) + (p4[2] + p4[3]);
        psum += __shfl_xor(psum, 32);
        lsum += psum;

        // P^T -> B-fragments: cvt_pk + permlane32_swap
        u32x4 pf0, pf1, pf2, pf3;
#define MKFRAG(sv, base_, dst) { \
        unsigned int c0 = pkbf(sv[base_+0], sv[base_+1]); \
        unsigned int c1 = pkbf(sv[base_+2], sv[base_+3]); \
        unsigned int c2 = pkbf(sv[base_+4], sv[base_+5]); \
        unsigned int c3 = pkbf(sv[base_+6], sv[base_+7]); \
        pl32swap(c0, c2); pl32swap(c1, c3); \
        dst[0] = c0; dst[1] = c1; dst[2] = c2; dst[3] = c3; }
        MKFRAG(s0, 0, pf0)
        MKFRAG(s0, 8, pf1)
        MKFRAG(s1, 0, pf2)
        MKFRAG(s1, 8, pf3)
#undef MKFRAG

        // O^T += V^T * P^T : A = Vt (row = d), B = P (col = q-row)
        __builtin_amdgcn_s_setprio(1);
#define PVSTEP(kc, pf) { \
        int cb = (kc * 16 + hi * 8) * 2; \
        int xr = ((c & 7) << 4); \
        bf16x8 vf0 = *(const bf16x8*)(Vsb + c * 128 + (cb ^ xr)); \
        bf16x8 vf1 = *(const bf16x8*)(Vsb + (32 + c) * 128 + (cb ^ xr)); \
        bf16x8 ph = u2h(pf); \
        oa0 = mfma32(vf0, ph, oa0); \
        oa1 = mfma32(vf1, ph, oa1); }
        PVSTEP(0, pf0)
        PVSTEP(1, pf1)
        PVSTEP(2, pf2)
        PVSTEP(3, pf3)
#undef PVSTEP
        __builtin_amdgcn_s_setprio(0);

        __syncthreads();                 // all reads done before restage
    }

    // ---- merge the two key-groups' (m, l, O) ----
    // lane-major overlay: Om[wg][r 0..31][lane] floats, ml[wg][0..1][lane]
    float* Om = (float*)lds;                       // 4*32*64*4 = 32 KB
    float* ml = (float*)(lds + 32768);             // 4*2*64*4  = 2 KB
    if (g == 1) {
        float* o = Om + wg * 2048 + l;
#pragma unroll
        for (int r = 0; r < 16; ++r) o[r * 64]        = oa0[r];
#pragma unroll
        for (int r = 0; r < 16; ++r) o[(16 + r) * 64] = oa1[r];
        ml[wg * 128 + l]      = m;
        ml[wg * 128 + 64 + l] = lsum;
    }
    __syncthreads();
    if (g == 1) return;

    float m2 = ml[wg * 128 + l];
    float l2 = ml[wg * 128 + 64 + l];
    float M  = fmaxf(m, m2);
    float a1 = fexp2(m - M), a2 = fexp2(m2 - M);
    float L  = lsum * a1 + l2 * a2;
    float rn = 1.0f / L;
    const float* o2 = Om + wg * 2048 + l;

    // normalize, write O^T back as O[b, t, h*64 + d]
    int b = bh >> 4, h = bh & 15;
    unsigned short* obase = ob + ((size_t)(b * TT + qrow)) * DD + h * 64;
#pragma unroll
    for (int gq = 0; gq < 4; ++gq) {
        u16x4 o0, o1;
#pragma unroll
        for (int e = 0; e < 4; ++e) {
            int r = gq * 4 + e;
            o0[e] = f2b((oa0[r] * a1 + o2[r * 64] * a2) * rn);
            o1[e] = f2b((oa1[r] * a1 + o2[(16 + r) * 64] * a2) * rn);
        }
        *(u16x4*)(obase + 8 * gq + 4 * hi)      = o0;   // d = e + 8gq + 4hi (db=0)
        *(u16x4*)(obase + 32 + 8 * gq + 4 * hi) = o1;   // db=1
    }
}

// ---------------- launcher ----------------
extern "C" void kernel_launch(void* const* d_in, const int* in_sizes, int n_in,
                              void* d_out, int out_size, void* d_ws, size_t ws_size,
                              hipStream_t stream) {
    const float* x    = (const float*)d_in[0];
    const float* Wqkv = (const float*)d_in[1];
    const float* bqkv = (const float*)d_in[2];
    const float* Wo   = (const float*)d_in[3];
    const float* bo   = (const float*)d_in[4];
    float* out = (float*)d_out;

    unsigned short* xb  = (unsigned short*)d_ws;        // [4096,1024]
    unsigned short* wqb = xb  + 4096 * 1024;            // [3072,1024]  (contiguous
    unsigned short* wob = wqb + 3072 * 1024;            // [1024,1024]   with xb)
    unsigned short* q   = wob + 1024 * 1024;            // [B,H,T,DH]
    unsigned short* k   = q   + 2 * 16 * 2048 * 64;     // [B,H,T,DH]
    unsigned short* vt  = k   + 2 * 16 * 2048 * 64;     // [B,H,DH,T]
    unsigned short* ob  = vt  + 2 * 16 * 2048 * 64;     // [4096,1024]

    // one conversion kernel for x|Wqkv|Wo (dest regions contiguous): 8192x256
    f2b3_kernel<<<dim3(8192), dim3(256), 0, stream>>>(x, Wqkv, Wo, xb);

    // QKV projection: M=4096, N=3072, K=1024
    gemm_bt<128, 0><<<dim3(24, 32), dim3(256), 0, stream>>>(xb, wqb, bqkv, 3072, 1024,
                                                            q, k, vt, nullptr);
    // attention: 512 blocks x 512 threads (2 key-groups), 34 KB dynamic LDS
    attn<<<dim3(512), dim3(512), 34816, stream>>>(q, k, vt, ob);

    // output projection: M=4096, N=1024, K=1024 (BN=64 -> 512 blocks)
    gemm_bt<64, 1><<<dim3(16, 32), dim3(256), 0, stream>>>(ob, wob, bo, 1024, 1024,
                                                           nullptr, nullptr, nullptr, out);
}

// Round 8
// 109.758 us; speedup vs baseline: 1.1960x; 1.0938x over previous
//
#include <hip/hip_runtime.h>

// Problem constants: B=2, T=2048, D=1024, H=16, DH=64
#define TT 2048
#define DD 1024
#define HH 16
#define DHH 64

typedef __attribute__((ext_vector_type(4)))  float  f32x4;
typedef __attribute__((ext_vector_type(16))) float  f32x16;
typedef __attribute__((ext_vector_type(8)))  short  bf16x8;   // 8 bf16 in 4 VGPRs
typedef __attribute__((ext_vector_type(4)))  float  f4;
typedef __attribute__((ext_vector_type(4)))  unsigned short u16x4;
typedef __attribute__((ext_vector_type(4)))  unsigned int   u32x4;

// fp32 -> bf16 round-to-nearest-even
__device__ __forceinline__ unsigned short f2b(float f) {
    union { float f; unsigned int u; } v; v.f = f;
    unsigned int r = v.u + 0x7fffu + ((v.u >> 16) & 1u);
    return (unsigned short)(r >> 16);
}

// async global->LDS, 16B per lane; LDS dest must be wave-uniform base + lane*16
__device__ __forceinline__ void gl_lds16(const void* g, void* l) {
    __builtin_amdgcn_global_load_lds(
        (const __attribute__((address_space(1))) unsigned int*)g,
        (__attribute__((address_space(3))) unsigned int*)l, 16, 0, 0);
}

__device__ __forceinline__ f32x16 mfma32(bf16x8 a, bf16x8 b, f32x16 c) {
    return __builtin_amdgcn_mfma_f32_32x32x16_bf16(a, b, c, 0, 0, 0);
}

// 2^x via v_exp_f32
__device__ __forceinline__ float fexp2(float x) {
    float r; asm("v_exp_f32 %0, %1" : "=v"(r) : "v"(x)); return r;
}

// pack two f32 -> u32 of 2 bf16 (lo = a, hi = b)
__device__ __forceinline__ unsigned int pkbf(float a, float b) {
    unsigned int r;
    asm("v_cvt_pk_bf16_f32 %0, %1, %2" : "=v"(r) : "v"(a), "v"(b));
    return r;
}

// v_permlane32_swap_b32: a'[32+i]=b[i]; b'[i]=a[32+i]
__device__ __forceinline__ void pl32swap(unsigned int& a, unsigned int& b) {
    asm("v_permlane32_swap_b32 %0, %1" : "+v"(a), "+v"(b));
}

__device__ __forceinline__ bf16x8 u2h(u32x4 u) {
    union { u32x4 u; bf16x8 h; } x; x.u = u; return x.h;
}

// ---------------- fp32 -> bf16 conversion: one kernel for all three inputs ----
// Destinations xb|wqb|wob are contiguous in ws; flat f4 index picks the source.
// sizes (f4 units): x 1048576, Wqkv 786432 (cum 1835008), Wo 262144 (tot 2097152)
__global__ void f2b3_kernel(const float* __restrict__ x, const float* __restrict__ wq,
                            const float* __restrict__ wo, unsigned short* __restrict__ d) {
    int i = blockIdx.x * blockDim.x + threadIdx.x;    // grid exactly 2097152 threads
    const float* s; int off;
    if (i < 1048576)      { s = x;  off = i; }
    else if (i < 1835008) { s = wq; off = i - 1048576; }
    else                  { s = wo; off = i - 1835008; }
    f4 v = ((const f4*)s)[off];
    u16x4 o;
    o[0] = f2b(v[0]); o[1] = f2b(v[1]); o[2] = f2b(v[2]); o[3] = f2b(v[3]);
    ((u16x4*)d)[i] = o;
}

// ---------------- GEMM: C[M,N] = A[M,K] * Bm[N,K]^T + bias ----------------
// 128 x BN tile, 4 waves (2x2), 2-phase double-buffered LDS staging.
// 1D grid with 2D XCD-chunked swizzle: each XCD owns an 8bm x BNCH bn rectangle
// (working set A 2MB + B <=3MB -> L2-resident), bm-fastest within the chunk so
// 8 consecutive same-XCD blocks reuse one hot B-panel.
// MODE 0 (BN=128, grid 768): QKV epilogue -> q scaled by 0.125*log2e,
//   k [B,H,T,DH], vt [B,H,DH,T] (vt packed as u16x4: 4 consecutive t per store)
// MODE 1 (BN=64, grid 512): fp32 out + bias (final projection)
template<int BN, int MODE>
__global__ __launch_bounds__(256) void gemm_bt(
    const unsigned short* __restrict__ A, const unsigned short* __restrict__ Bm,
    const float* __restrict__ bias, int N, int K,
    unsigned short* __restrict__ q, unsigned short* __restrict__ k,
    unsigned short* __restrict__ vt, float* __restrict__ outf)
{
    constexpr int NB  = BN / 32;        // B-frags per wave
    constexpr int ASZ = 128 * 32;       // shorts per A tile
    constexpr int BSZ = BN * 32;        // shorts per B tile
    constexpr int BNCH = (MODE == 0 ? 12 : 8);   // bn per XCD chunk
    __shared__ unsigned short lds[2 * (ASZ + BSZ)];

    int tid = threadIdx.x;
    int l = tid & 63, w = tid >> 6;
    int wr = w >> 1, wc = w & 1;
    int lr = l & 15, lk = (l >> 4) * 8;

    // XCD 2D-chunk swizzle (consecutive hw blocks round-robin XCDs; lin&7 = XCD)
    int lin = blockIdx.x;
    int cx = lin & 7, ii = lin >> 3;
    int bm = (cx >> 1) * 8 + (ii & 7);
    int bn = (cx & 1) * BNCH + (ii >> 3);

    f32x4 acc[4][NB] = {};

    const unsigned short* Ag = A + (size_t)(bm * 128) * K;
    const unsigned short* Bg = Bm + (size_t)(bn * BN) * K;

    auto stage = [&](int buf, int k0) {
        unsigned short* As = lds + buf * (ASZ + BSZ);
        unsigned short* Bs = As + ASZ;
#pragma unroll
        for (int r = 0; r < 2; ++r) {
            int e = r * 256 + tid;
            int row = e >> 2, kc = (e & 3) * 8;
            gl_lds16(Ag + (size_t)row * K + k0 + kc, &As[e * 8]);
        }
#pragma unroll
        for (int r = 0; r < BN / 64; ++r) {
            int e = r * 256 + tid;
            int row = e >> 2, kc = (e & 3) * 8;
            gl_lds16(Bg + (size_t)row * K + k0 + kc, &Bs[e * 8]);
        }
    };

    stage(0, 0);
    __syncthreads();
    int cur = 0;
    for (int k0 = 0; k0 < K; k0 += 32) {
        if (k0 + 32 < K) stage(cur ^ 1, k0 + 32);   // prefetch next tile
        const unsigned short* As = lds + cur * (ASZ + BSZ);
        const unsigned short* Bs = As + ASZ;
        bf16x8 a[4], b[NB];
#pragma unroll
        for (int i = 0; i < 4; ++i)
            a[i] = *(const bf16x8*)&As[(wr * 64 + i * 16 + lr) * 32 + lk];
#pragma unroll
        for (int j = 0; j < NB; ++j)
            b[j] = *(const bf16x8*)&Bs[(wc * (BN / 2) + j * 16 + lr) * 32 + lk];
        __builtin_amdgcn_s_setprio(1);
#pragma unroll
        for (int i = 0; i < 4; ++i)
#pragma unroll
            for (int j = 0; j < NB; ++j)
                acc[i][j] = __builtin_amdgcn_mfma_f32_16x16x32_bf16(a[i], b[j], acc[i][j], 0, 0, 0);
        __builtin_amdgcn_s_setprio(0);
        __syncthreads();
        cur ^= 1;
    }

#pragma unroll
    for (int i = 0; i < 4; ++i) {
#pragma unroll
        for (int j = 0; j < NB; ++j) {
            int row0 = bm * 128 + wr * 64 + i * 16 + (l >> 4) * 4;
            int col  = bn * BN + wc * (BN / 2) + j * 16 + (l & 15);
            float bv = bias[col];
            float val[4];
#pragma unroll
            for (int r = 0; r < 4; ++r) val[r] = acc[i][j][r] + bv;
            if (MODE == 0) {
                int which = col >> 10, rem = col & 1023;
                int h = rem >> 6, d = rem & 63;
                int b = row0 >> 11, t0 = row0 & 2047;   // rows r=0..3 same b (t0 %4==0)
                if (which == 0) {
                    // fold softmax scale AND log2(e): 0.125 * 1.4426950408889634
#pragma unroll
                    for (int r = 0; r < 4; ++r)
                        q[((size_t)((b * HH + h) * TT + t0 + r)) * DHH + d] =
                            f2b(val[r] * 0.18033688011112042f);
                } else if (which == 1) {
#pragma unroll
                    for (int r = 0; r < 4; ++r)
                        k[((size_t)((b * HH + h) * TT + t0 + r)) * DHH + d] = f2b(val[r]);
                } else {
                    // vt: 4 consecutive t at fixed d -> one 8B packed store
                    u16x4 pk;
#pragma unroll
                    for (int r = 0; r < 4; ++r) pk[r] = f2b(val[r]);
                    *(u16x4*)(vt + ((size_t)((b * HH + h) * DHH + d)) * TT + t0) = pk;
                }
            } else {
#pragma unroll
                for (int r = 0; r < 4; ++r)
                    outf[(size_t)(row0 + r) * N + col] = val[r];
            }
        }
    }
}

// ---------------- flash attention: split-K, swapped-operand 32x32 ----------------
// grid 512 blocks (XCD-swizzled), 8 waves = 2 key-groups x 4 waves.
// Group g handles keys [g*1024, g*1024+1024) over the block's 128 q-rows;
// each wave owns 32 q-rows. 4096 waves total -> 4 waves/SIMD.
// Per group: single-buffered KVBLK=64 staging (r2/r5 structure, the measured best).
// S^T = K*Q^T (lane owns one q-row), per-lane scalar defer-max softmax state
// (PROVEN numerics — the r6 fixed-base variant failed accuracy 13x).
// Row-sum kept as per-lane HALF sums (legal: m is uniform across the lane/lane+32
// pair since tm is shfl-combined before the max update); single shfl at the end.
// P -> B-frag via cvt_pk_bf16 + permlane32_swap, O^T = V^T * P^T.
// End: group 1 publishes (m,l,O) via lane-major LDS; group 0 merges + writes.
__global__ __launch_bounds__(512, 4) void attn(
    const unsigned short* __restrict__ qb,
    const unsigned short* __restrict__ kb,
    const unsigned short* __restrict__ vtb,
    unsigned short* __restrict__ ob)
{
    extern __shared__ char lds[];   // staging: [2 groups][K 8KB | V 8KB] = 32KB
                                    // merge overlay: Om 32KB + ml 2KB = 34KB

    int tid = threadIdx.x;
    int l = tid & 63, w = tid >> 6;      // w 0..7
    int g = w >> 2, wg = w & 3;          // key-group, wave-in-group
    int hi = l >> 5, c = l & 31;
    int tig = tid & 255;                 // thread-in-group

    // XCD swizzle: 4 heads' K/V per XCD L2
    int lin = blockIdx.x;                // 0..511
    int swz = (lin & 7) * 64 + (lin >> 3);
    int bh = swz >> 4;
    int qrow = (swz & 15) * 128 + wg * 32 + c;

    // Q as B-fragments: col = qrow (lane&31), k = d = kd*16 + hi*8 + j
    bf16x8 qf[4];
    const unsigned short* qg = qb + ((size_t)bh * TT + qrow) * DHH;
#pragma unroll
    for (int kd = 0; kd < 4; ++kd)
        qf[kd] = *(const bf16x8*)(qg + kd * 16 + hi * 8);

    f32x16 oa0 = {}, oa1 = {};
    float m = -1e30f, lsum = 0.f;        // lsum = this lane's HALF row-sum

    // group key-range base folded into pointers
    const char* kgl = (const char*)(kb + (size_t)bh * TT * DHH) + (size_t)g * 1024 * 128;
    const char* vgl = (const char*)(vtb + (size_t)bh * DHH * TT) + (size_t)g * 1024 * 2;
    char* base = lds + g * 16384;        // this group's staging slice

    for (int kt0 = 0; kt0 < 1024; kt0 += 64) {
        // stage K [64 key][64 d] and Vt [64 d][64 key]; rows 128B, XOR-swizzled
        // via pre-swizzled global source (gl_lds dest must stay linear)
#pragma unroll
        for (int r = 0; r < 2; ++r) {
            int p = r * 4096 + tig * 16;
            int rw = p >> 7, qq = p & 127;
            int sw = qq ^ ((rw & 7) << 4);
            gl_lds16(kgl + (size_t)(kt0 + rw) * 128 + sw, base + p);
            gl_lds16(vgl + (size_t)rw * (TT * 2) + kt0 * 2 + sw, base + 8192 + p);
        }
        __syncthreads();
        const char* Ksb = base;
        const char* Vsb = base + 8192;

        // S^T = K * Q^T : D rows = key, cols = q-row (lane&31)
        f32x16 s0 = {}, s1 = {};
        __builtin_amdgcn_s_setprio(1);
#pragma unroll
        for (int kd = 0; kd < 4; ++kd) {
            int cb = (kd * 16 + hi * 8) * 2;
            int xr = cb ^ ((c & 7) << 4);
            bf16x8 kf0 = *(const bf16x8*)(Ksb + c * 128 + xr);
            bf16x8 kf1 = *(const bf16x8*)(Ksb + (32 + c) * 128 + xr);
            s0 = mfma32(kf0, qf[kd], s0);
            s1 = mfma32(kf1, qf[kd], s1);
        }
        __builtin_amdgcn_s_setprio(0);

        // tile max (log2 domain), max3-shaped tree
        float mx0 = fmaxf(fmaxf(s0[0], s0[1]), s0[2]);
        float mx1 = fmaxf(fmaxf(s0[3], s0[4]), s0[5]);
        float mx2 = fmaxf(fmaxf(s0[6], s0[7]), s0[8]);
        float mx3 = fmaxf(fmaxf(s0[9], s0[10]), s0[11]);
        float mx4 = fmaxf(fmaxf(s0[12], s0[13]), s0[14]);
        float mx5 = fmaxf(fmaxf(s0[15], s1[0]), s1[1]);
        float mx6 = fmaxf(fmaxf(s1[2], s1[3]), s1[4]);
        float mx7 = fmaxf(fmaxf(s1[5], s1[6]), s1[7]);
        float mx8 = fmaxf(fmaxf(s1[8], s1[9]), s1[10]);
        float mx9 = fmaxf(fmaxf(s1[11], s1[12]), s1[13]);
        float mxA = fmaxf(s1[14], s1[15]);
        float t0 = fmaxf(fmaxf(mx0, mx1), mx2);
        float t1 = fmaxf(fmaxf(mx3, mx4), mx5);
        float t2 = fmaxf(fmaxf(mx6, mx7), mx8);
        float t3 = fmaxf(mx9, mxA);
        float tm = fmaxf(fmaxf(t0, t1), fmaxf(t2, t3));
        tm = fmaxf(tm, __shfl_xor(tm, 32, 64));    // m uniform across half-pair

        float nm = fmaxf(m, tm);
        if (!__all(nm - m <= 8.f)) {        // T13: defer rescale unless max grew >8
            float corr = fexp2(m - nm);
            lsum *= corr;
#pragma unroll
            for (int r = 0; r < 16; ++r) { oa0[r] *= corr; oa1[r] *= corr; }
            m = nm;
        }

        float p4[4] = {0.f, 0.f, 0.f, 0.f};
#pragma unroll
        for (int r = 0; r < 16; ++r) { s0[r] = fexp2(s0[r] - m); p4[r & 3] += s0[r]; }
#pragma unroll
        for (int r = 0; r < 16; ++r) { s1[r] = fexp2(s1[r] - m); p4[r & 3] += s1[r]; }
        lsum += (p4[0] + p4[1]) + (p4[2] + p4[3]);   // per-lane half-sum (no shfl)

        // P^T -> B-fragments: cvt_pk + permlane32_swap
        u32x4 pf0, pf1, pf2, pf3;
#define MKFRAG(sv, base_, dst) { \
        unsigned int c0 = pkbf(sv[base_+0], sv[base_+1]); \
        unsigned int c1 = pkbf(sv[base_+2], sv[base_+3]); \
        unsigned int c2 = pkbf(sv[base_+4], sv[base_+5]); \
        unsigned int c3 = pkbf(sv[base_+6], sv[base_+7]); \
        pl32swap(c0, c2); pl32swap(c1, c3); \
        dst[0] = c0; dst[1] = c1; dst[2] = c2; dst[3] = c3; }
        MKFRAG(s0, 0, pf0)
        MKFRAG(s0, 8, pf1)
        MKFRAG(s1, 0, pf2)
        MKFRAG(s1, 8, pf3)
#undef MKFRAG

        // O^T += V^T * P^T : A = Vt (row = d), B = P (col = q-row)
        __builtin_amdgcn_s_setprio(1);
#define PVSTEP(kc, pf) { \
        int cb = (kc * 16 + hi * 8) * 2; \
        int xr = ((c & 7) << 4); \
        bf16x8 vf0 = *(const bf16x8*)(Vsb + c * 128 + (cb ^ xr)); \
        bf16x8 vf1 = *(const bf16x8*)(Vsb + (32 + c) * 128 + (cb ^ xr)); \
        bf16x8 ph = u2h(pf); \
        oa0 = mfma32(vf0, ph, oa0); \
        oa1 = mfma32(vf1, ph, oa1); }
        PVSTEP(0, pf0)
        PVSTEP(1, pf1)
        PVSTEP(2, pf2)
        PVSTEP(3, pf3)
#undef PVSTEP
        __builtin_amdgcn_s_setprio(0);

        __syncthreads();                 // all reads done before restage
    }

    // ---- merge the two key-groups' (m, half-l, O) ----
    // lane-major overlay: Om[wg][r 0..31][lane] floats, ml[wg][0..1][lane]
    float* Om = (float*)lds;                       // 4*32*64*4 = 32 KB
    float* ml = (float*)(lds + 32768);             // 4*2*64*4  = 2 KB
    if (g == 1) {
        float* o = Om + wg * 2048 + l;
#pragma unroll
        for (int r = 0; r < 16; ++r) o[r * 64]        = oa0[r];
#pragma unroll
        for (int r = 0; r < 16; ++r) o[(16 + r) * 64] = oa1[r];
        ml[wg * 128 + l]      = m;
        ml[wg * 128 + 64 + l] = lsum;
    }
    __syncthreads();
    if (g == 1) return;

    float m2 = ml[wg * 128 + l];
    float l2 = ml[wg * 128 + 64 + l];
    float M  = fmaxf(m, m2);
    float a1 = fexp2(m - M), a2 = fexp2(m2 - M);
    float Lh = lsum * a1 + l2 * a2;                // still a half-sum
    float L  = Lh + __shfl_xor(Lh, 32, 64);        // combine the two halves
    float rn = 1.0f / L;
    const float* o2 = Om + wg * 2048 + l;

    // normalize, write O^T back as O[b, t, h*64 + d]
    int b = bh >> 4, h = bh & 15;
    unsigned short* obase = ob + ((size_t)(b * TT + qrow)) * DD + h * 64;
#pragma unroll
    for (int gq = 0; gq < 4; ++gq) {
        u16x4 o0, o1;
#pragma unroll
        for (int e = 0; e < 4; ++e) {
            int r = gq * 4 + e;
            o0[e] = f2b((oa0[r] * a1 + o2[r * 64] * a2) * rn);
            o1[e] = f2b((oa1[r] * a1 + o2[(16 + r) * 64] * a2) * rn);
        }
        *(u16x4*)(obase + 8 * gq + 4 * hi)      = o0;   // d = e + 8gq + 4hi (db=0)
        *(u16x4*)(obase + 32 + 8 * gq + 4 * hi) = o1;   // db=1
    }
}

// ---------------- launcher ----------------
extern "C" void kernel_launch(void* const* d_in, const int* in_sizes, int n_in,
                              void* d_out, int out_size, void* d_ws, size_t ws_size,
                              hipStream_t stream) {
    const float* x    = (const float*)d_in[0];
    const float* Wqkv = (const float*)d_in[1];
    const float* bqkv = (const float*)d_in[2];
    const float* Wo   = (const float*)d_in[3];
    const float* bo   = (const float*)d_in[4];
    float* out = (float*)d_out;

    unsigned short* xb  = (unsigned short*)d_ws;        // [4096,1024]
    unsigned short* wqb = xb  + 4096 * 1024;            // [3072,1024]  (contiguous
    unsigned short* wob = wqb + 3072 * 1024;            // [1024,1024]   with xb)
    unsigned short* q   = wob + 1024 * 1024;            // [B,H,T,DH]
    unsigned short* k   = q   + 2 * 16 * 2048 * 64;     // [B,H,T,DH]
    unsigned short* vt  = k   + 2 * 16 * 2048 * 64;     // [B,H,DH,T]
    unsigned short* ob  = vt  + 2 * 16 * 2048 * 64;     // [4096,1024]

    // one conversion kernel for x|Wqkv|Wo (dest regions contiguous): 8192x256
    f2b3_kernel<<<dim3(8192), dim3(256), 0, stream>>>(x, Wqkv, Wo, xb);

    // QKV projection: M=4096, N=3072, K=1024 (1D grid, XCD 2D-chunk swizzle)
    gemm_bt<128, 0><<<dim3(768), dim3(256), 0, stream>>>(xb, wqb, bqkv, 3072, 1024,
                                                         q, k, vt, nullptr);
    // attention: 512 blocks x 512 threads (2 key-groups), 34 KB dynamic LDS
    attn<<<dim3(512), dim3(512), 34816, stream>>>(q, k, vt, ob);

    // output projection: M=4096, N=1024, K=1024 (1D grid, XCD 2D-chunk swizzle)
    gemm_bt<64, 1><<<dim3(512), dim3(256), 0, stream>>>(ob, wob, bo, 1024, 1024,
                                                        nullptr, nullptr, nullptr, out);
}